// Round 15
// baseline (278.292 us; speedup 1.0000x reference)
//
#include <hip/hip_runtime.h>
#include <hip/hip_fp8.h>
#include <math.h>

#define NN   100000
#define NE   1600000
#define DIN  128
#define DH   64
#define DOUT 40
#define BN_EPS 1e-5f
#define KB   256   // buckets
#define BSZ  391   // nodes per bucket (256*391 = 100096 >= NN)
#define PBLK 256   // partition blocks
#define PE   6250  // NE / PBLK exact
#define N2   (KB * PBLK)  // 65536
#define NB2  64    // N2 / 1024
#define GB2  782   // ceil(NN/128) -- 128 rows per GEMM block

typedef unsigned short ushort_t;
typedef unsigned int uint_t;
typedef unsigned char uchar_t;

__device__ __forceinline__ float bf2f(ushort_t v) {
  union { uint_t u; float f; } w;
  w.u = ((uint_t)v) << 16;
  return w.f;
}
__device__ __forceinline__ ushort_t f2bf(float f) {  // RNE
  union { float f; uint_t u; } w;
  w.f = f;
  uint_t u = w.u;
  u += 0x7fffu + ((u >> 16) & 1u);
  return (ushort_t)(u >> 16);
}
__device__ __forceinline__ uchar_t f2e4m3(float f) {
  __hip_fp8_e4m3 q(f);  // OCP e4m3fn, RNE + satfinite
  return (uchar_t)q.__x;
}
__device__ __forceinline__ float e4m32f(uchar_t b) {
  __hip_fp8_e4m3 q;
  q.__x = (__hip_fp8_storage_t)b;
  return (float)q;
}

// ---------------- pass A: per-block bucket histogram (+stats zero) ----------------
__global__ void __launch_bounds__(512) k_cnt(const int* __restrict__ dst,
                                             int* __restrict__ cntmat,
                                             float* __restrict__ stats) {
  __shared__ int h[KB];
  int t = threadIdx.x, blk = blockIdx.x;
  if (t < KB) h[t] = 0;
  if (blk == 0 && t < 128) stats[t] = 0.0f;
  __syncthreads();
  int base = blk * PE;  // PE = 6250 = 2*3125
  const int2* d2 = (const int2*)(dst + base);
  for (int i = t; i < PE / 2; i += 512) {
    int2 v = d2[i];
    atomicAdd(&h[v.x / BSZ], 1);
    atomicAdd(&h[v.y / BSZ], 1);
  }
  __syncthreads();
  if (t < KB) cntmat[t * PBLK + blk] = h[t];
}

// ---------------- scan C/D: exclusive scan of cntmat (65536, bucket-major) ----------------
__global__ void __launch_bounds__(1024) k_scanC(const int* __restrict__ cntmat,
                                                int* __restrict__ cscan,
                                                int* __restrict__ ctot) {
  __shared__ int sh[1024];
  int t = threadIdx.x, b = blockIdx.x;
  int i = b * 1024 + t;  // exact: 64*1024 = 65536
  int v = cntmat[i];
  sh[t] = v;
  __syncthreads();
  for (int off = 1; off < 1024; off <<= 1) {
    int u = (t >= off) ? sh[t - off] : 0;
    __syncthreads();
    sh[t] += u;
    __syncthreads();
  }
  cscan[i] = sh[t] - v;
  if (t == 1023) ctot[b] = sh[t];
}

__global__ void __launch_bounds__(1024) k_scanD(int* __restrict__ cscan,
                                                const int* __restrict__ ctot) {
  __shared__ int sh[NB2];
  int t = threadIdx.x, b = blockIdx.x;
  if (t < NB2) sh[t] = ctot[t];
  __syncthreads();
  for (int off = 1; off < NB2; off <<= 1) {
    int u = (t >= off && t < NB2) ? sh[t - off] : 0;
    __syncthreads();
    if (t < NB2) sh[t] += u;
    __syncthreads();
  }
  if (b > 0) cscan[b * 1024 + t] += sh[b - 1];
}

// ---------------- pass C: scatter edges to deterministic bucket slots ----------------
// payload = (src << 9) | d_local   (src < 2^17, d_local < 391 < 2^9)
__global__ void __launch_bounds__(512) k_scat(const int* __restrict__ src,
                                              const int* __restrict__ dst,
                                              const int* __restrict__ cscan,
                                              uint_t* __restrict__ bpair) {
  __shared__ int cur[KB];
  int t = threadIdx.x, blk = blockIdx.x;
  if (t < KB) cur[t] = cscan[t * PBLK + blk];
  __syncthreads();
  int base = blk * PE;
  for (int i = t; i < PE; i += 512) {
    int e = base + i;
    int d = dst[e], s = src[e];
    int b = d / BSZ;
    int pos = atomicAdd(&cur[b], 1);
    bpair[pos] = ((uint_t)s << 9) | (uint_t)(d - b * BSZ);
  }
}

// ---- fused: per-bucket count + local scan -> rowptr/hist/dinv + CSR fill ----
__global__ void __launch_bounds__(512) k_cfill(const uint_t* __restrict__ bpair,
                                               const int* __restrict__ cscan,
                                               int* __restrict__ rowptr,
                                               int* __restrict__ hist,
                                               float* __restrict__ dinv,
                                               int* __restrict__ csr) {
  __shared__ int cnt[BSZ];
  __shared__ int loc[BSZ];
  __shared__ int cur[BSZ];
  __shared__ int sh[512];
  int b = blockIdx.x, t = threadIdx.x;
  for (int i = t; i < BSZ; i += 512) { cnt[i] = 0; cur[i] = 0; }
  __syncthreads();
  int start = cscan[b * PBLK];
  int end = (b + 1 < KB) ? cscan[(b + 1) * PBLK] : NE;
  for (int i = start + t; i < end; i += 512) atomicAdd(&cnt[bpair[i] & 511u], 1);
  __syncthreads();
  int v = (t < BSZ) ? cnt[t] : 0;
  sh[t] = v;
  __syncthreads();
  for (int off = 1; off < 512; off <<= 1) {
    int u = (t >= off) ? sh[t - off] : 0;
    __syncthreads();
    sh[t] += u;
    __syncthreads();
  }
  if (t < BSZ) {
    int excl = sh[t] - v;
    loc[t] = excl;
    int node = b * BSZ + t;
    if (node < NN) {
      rowptr[node] = start + excl;
      hist[node] = v;
      dinv[node] = rsqrtf(1.0f + (float)v);
    }
  }
  __syncthreads();
  for (int i = start + t; i < end; i += 512) {
    uint_t u = bpair[i];
    int dloc = (int)(u & 511u);
    int pos = start + loc[dloc] + atomicAdd(&cur[dloc], 1);
    csr[pos] = (int)(u >> 9);
  }
}

// ---------------- h1pre = (x0 @ W1) * dinv, stored bf16 ----------------
// 4 threads per row (16 ch each), 2 rows per thread, W1 staged in LDS.
__global__ void __launch_bounds__(256) k_gemm1(const float* __restrict__ X,
                                               const float* __restrict__ W,
                                               const float* __restrict__ dinv,
                                               ushort_t* __restrict__ Hb) {
  __shared__ float w[DIN * DH];  // 32 KB
  int t = threadIdx.x;
  {
    const float4* ws = (const float4*)W;
    float4* wd = (float4*)w;
#pragma unroll
    for (int i = 0; i < DIN * DH / 4 / 256; ++i) wd[t + i * 256] = ws[t + i * 256];
  }
  __syncthreads();
  int rr = t >> 2, q = t & 3;
  int row0 = blockIdx.x * 128 + rr;
  int row1 = row0 + 64;
  bool v0 = row0 < NN, v1 = row1 < NN;
  float acc0[16], acc1[16];
#pragma unroll
  for (int j = 0; j < 16; ++j) { acc0[j] = 0.0f; acc1[j] = 0.0f; }
  const float4* xr0 = (const float4*)(X + (size_t)row0 * DIN);
  const float4* xr1 = (const float4*)(X + (size_t)row1 * DIN);
  const float4 z4 = make_float4(0.f, 0.f, 0.f, 0.f);
  for (int k4 = 0; k4 < DIN / 4; ++k4) {
    float4 a = v0 ? xr0[k4] : z4;
    float4 b = v1 ? xr1[k4] : z4;
#pragma unroll
    for (int kk = 0; kk < 4; ++kk) {
      const float* wr = w + (k4 * 4 + kk) * DH + q * 16;
      float xa = (&a.x)[kk], xb = (&b.x)[kk];
#pragma unroll
      for (int j = 0; j < 16; ++j) {
        acc0[j] = fmaf(xa, wr[j], acc0[j]);
        acc1[j] = fmaf(xb, wr[j], acc1[j]);
      }
    }
  }
  if (v0) {
    float di = dinv[row0];
    uint_t pk[8];
#pragma unroll
    for (int j = 0; j < 8; ++j)
      pk[j] = (uint_t)f2bf(acc0[2 * j] * di) | ((uint_t)f2bf(acc0[2 * j + 1] * di) << 16);
    uint4* o = (uint4*)(Hb + (size_t)row0 * DH + q * 16);
    o[0] = make_uint4(pk[0], pk[1], pk[2], pk[3]);
    o[1] = make_uint4(pk[4], pk[5], pk[6], pk[7]);
  }
  if (v1) {
    float di = dinv[row1];
    uint_t pk[8];
#pragma unroll
    for (int j = 0; j < 8; ++j)
      pk[j] = (uint_t)f2bf(acc1[2 * j] * di) | ((uint_t)f2bf(acc1[2 * j + 1] * di) << 16);
    uint4* o = (uint4*)(Hb + (size_t)row1 * DH + q * 16);
    o[0] = make_uint4(pk[0], pk[1], pk[2], pk[3]);
    o[1] = make_uint4(pk[4], pk[5], pk[6], pk[7]);
  }
}

// ---- gather1 + BN stats: 2 nodes/wave, index-prefetch, non-temporal row loads ----
__global__ void __launch_bounds__(256) k_gather1(const int* __restrict__ csr,
                                                 const int* __restrict__ rowptr,
                                                 const int* __restrict__ cnt,
                                                 const float* __restrict__ dinv,
                                                 const ushort_t* __restrict__ Hb,
                                                 const float* __restrict__ bias,
                                                 float* __restrict__ Agg,
                                                 float* __restrict__ stats) {
  int lane = threadIdx.x & 63, w = threadIdx.x >> 6;
  int c = lane;
  int wid = blockIdx.x * 4 + w;
  int nw = gridDim.x * 4;
  float bc = bias[c];
  float s1 = 0.0f, s2 = 0.0f;
  for (int p = wid; p < NN / 2; p += nw) {
    int d0 = 2 * p, d1 = 2 * p + 1;
    int st0 = __builtin_amdgcn_readfirstlane(rowptr[d0]);
    int n0  = __builtin_amdgcn_readfirstlane(cnt[d0]);
    int st1 = __builtin_amdgcn_readfirstlane(rowptr[d1]);
    int n1  = __builtin_amdgcn_readfirstlane(cnt[d1]);
    const int* cs0 = csr + st0;
    const int* cs1 = csr + st1;
    float acc0 = bf2f(__builtin_nontemporal_load(&Hb[(size_t)d0 * DH + c]));
    float acc1 = bf2f(__builtin_nontemporal_load(&Hb[(size_t)d1 * DH + c]));
    int nmin = min(n0, n1);
    int k = 0;
    if (nmin >= 4) {
      int a0 = cs0[0], a1 = cs0[1], a2 = cs0[2], a3 = cs0[3];
      int b0 = cs1[0], b1 = cs1[1], b2 = cs1[2], b3 = cs1[3];
      for (; k + 8 <= nmin; k += 4) {
        ushort_t ra0 = __builtin_nontemporal_load(&Hb[(size_t)a0 * DH + c]);
        ushort_t ra1 = __builtin_nontemporal_load(&Hb[(size_t)a1 * DH + c]);
        ushort_t ra2 = __builtin_nontemporal_load(&Hb[(size_t)a2 * DH + c]);
        ushort_t ra3 = __builtin_nontemporal_load(&Hb[(size_t)a3 * DH + c]);
        ushort_t rb0 = __builtin_nontemporal_load(&Hb[(size_t)b0 * DH + c]);
        ushort_t rb1 = __builtin_nontemporal_load(&Hb[(size_t)b1 * DH + c]);
        ushort_t rb2 = __builtin_nontemporal_load(&Hb[(size_t)b2 * DH + c]);
        ushort_t rb3 = __builtin_nontemporal_load(&Hb[(size_t)b3 * DH + c]);
        a0 = cs0[k + 4]; a1 = cs0[k + 5]; a2 = cs0[k + 6]; a3 = cs0[k + 7];
        b0 = cs1[k + 4]; b1 = cs1[k + 5]; b2 = cs1[k + 6]; b3 = cs1[k + 7];
        acc0 += (bf2f(ra0) + bf2f(ra1)) + (bf2f(ra2) + bf2f(ra3));
        acc1 += (bf2f(rb0) + bf2f(rb1)) + (bf2f(rb2) + bf2f(rb3));
      }
      {
        ushort_t ra0 = __builtin_nontemporal_load(&Hb[(size_t)a0 * DH + c]);
        ushort_t ra1 = __builtin_nontemporal_load(&Hb[(size_t)a1 * DH + c]);
        ushort_t ra2 = __builtin_nontemporal_load(&Hb[(size_t)a2 * DH + c]);
        ushort_t ra3 = __builtin_nontemporal_load(&Hb[(size_t)a3 * DH + c]);
        ushort_t rb0 = __builtin_nontemporal_load(&Hb[(size_t)b0 * DH + c]);
        ushort_t rb1 = __builtin_nontemporal_load(&Hb[(size_t)b1 * DH + c]);
        ushort_t rb2 = __builtin_nontemporal_load(&Hb[(size_t)b2 * DH + c]);
        ushort_t rb3 = __builtin_nontemporal_load(&Hb[(size_t)b3 * DH + c]);
        acc0 += (bf2f(ra0) + bf2f(ra1)) + (bf2f(ra2) + bf2f(ra3));
        acc1 += (bf2f(rb0) + bf2f(rb1)) + (bf2f(rb2) + bf2f(rb3));
        k += 4;
      }
    }
    for (; k < nmin; ++k) {
      acc0 += bf2f(__builtin_nontemporal_load(&Hb[(size_t)cs0[k] * DH + c]));
      acc1 += bf2f(__builtin_nontemporal_load(&Hb[(size_t)cs1[k] * DH + c]));
    }
    int k0 = k;
    for (; k0 + 4 <= n0; k0 += 4) {
      int i0 = cs0[k0], i1 = cs0[k0 + 1], i2 = cs0[k0 + 2], i3 = cs0[k0 + 3];
      float f0 = bf2f(__builtin_nontemporal_load(&Hb[(size_t)i0 * DH + c]));
      float f1 = bf2f(__builtin_nontemporal_load(&Hb[(size_t)i1 * DH + c]));
      float f2 = bf2f(__builtin_nontemporal_load(&Hb[(size_t)i2 * DH + c]));
      float f3 = bf2f(__builtin_nontemporal_load(&Hb[(size_t)i3 * DH + c]));
      acc0 += (f0 + f1) + (f2 + f3);
    }
    for (; k0 < n0; ++k0) acc0 += bf2f(__builtin_nontemporal_load(&Hb[(size_t)cs0[k0] * DH + c]));
    int k1 = k;
    for (; k1 + 4 <= n1; k1 += 4) {
      int i0 = cs1[k1], i1 = cs1[k1 + 1], i2 = cs1[k1 + 2], i3 = cs1[k1 + 3];
      float f0 = bf2f(__builtin_nontemporal_load(&Hb[(size_t)i0 * DH + c]));
      float f1 = bf2f(__builtin_nontemporal_load(&Hb[(size_t)i1 * DH + c]));
      float f2 = bf2f(__builtin_nontemporal_load(&Hb[(size_t)i2 * DH + c]));
      float f3 = bf2f(__builtin_nontemporal_load(&Hb[(size_t)i3 * DH + c]));
      acc1 += (f0 + f1) + (f2 + f3);
    }
    for (; k1 < n1; ++k1) acc1 += bf2f(__builtin_nontemporal_load(&Hb[(size_t)cs1[k1] * DH + c]));
    float v0 = fmaf(acc0, dinv[d0], bc);
    float v1 = fmaf(acc1, dinv[d1], bc);
    Agg[(size_t)d0 * DH + c] = v0;
    Agg[(size_t)d1 * DH + c] = v1;
    s1 += v0 + v1;
    s2 += v0 * v0 + v1 * v1;
  }
  __shared__ float red[512];
  red[threadIdx.x] = s1;
  red[256 + threadIdx.x] = s2;
  __syncthreads();
  if (threadIdx.x < 64) {
    float a = red[c] + red[64 + c] + red[128 + c] + red[192 + c];
    float b = red[256 + c] + red[320 + c] + red[384 + c] + red[448 + c];
    atomicAdd(&stats[c], a);
    atomicAdd(&stats[64 + c], b);
  }
}

// -------- finalize BN: scale/shift; cvec = bl + b2@Wl_bot; W2b = W2 @ Wl_bot --------
__global__ void __launch_bounds__(256) k_bnfinal(const float* __restrict__ stats,
                                                 const float* __restrict__ g,
                                                 const float* __restrict__ be,
                                                 const float* __restrict__ b2,
                                                 const float* __restrict__ Wl,
                                                 const float* __restrict__ bl,
                                                 const float* __restrict__ W2,
                                                 float* __restrict__ scsh,
                                                 float* __restrict__ cvec,
                                                 float* __restrict__ W2b) {
  int t = threadIdx.x;
  if (t < 64) {
    float mean = stats[t] * (1.0f / NN);
    float var = stats[64 + t] * (1.0f / NN) - mean * mean;
    float sc = g[t] * rsqrtf(var + BN_EPS);
    scsh[t] = sc;
    scsh[64 + t] = be[t] - mean * sc;
  }
  if (t < DOUT) {
    float s = bl[t];
    for (int k = 0; k < DH; ++k) s = fmaf(b2[k], Wl[(DH + k) * DOUT + t], s);
    cvec[t] = s;
  }
  // W2b[k][j] = sum_m W2[k][m] * Wl[(64+m)*40 + j]
  {
    int k = t >> 2, jq = (t & 3) * 10;
    float a[10];
#pragma unroll
    for (int j = 0; j < 10; ++j) a[j] = 0.0f;
    for (int m = 0; m < DH; ++m) {
      float wv = W2[k * DH + m];
      const float* wl = Wl + (DH + m) * DOUT + jq;
#pragma unroll
      for (int j = 0; j < 10; ++j) a[j] = fmaf(wv, wl[j], a[j]);
    }
#pragma unroll
    for (int j = 0; j < 10; ++j) W2b[k * DOUT + jq + j] = a[j];
  }
}

// ---- x1 = relu(bn(agg1)); y1 = x1@Wl_top + cvec; z = fp8(dinv * (x1@W2b)) ----
__global__ void __launch_bounds__(256) k_bngemm2(const float* __restrict__ Agg1,
                                                 const float* __restrict__ scsh,
                                                 const float* __restrict__ dinv,
                                                 const float* __restrict__ Wl,
                                                 const float* __restrict__ W2b,
                                                 const float* __restrict__ cvec,
                                                 float* __restrict__ Y1,
                                                 uchar_t* __restrict__ Z) {
  __shared__ float wlt[DH * DOUT];  // 10 KB  (Wl rows 0..63)
  __shared__ float wzb[DH * DOUT];  // 10 KB  (W2 @ Wl_bot)
  __shared__ float ss[128];
  __shared__ float cvs[DOUT];
  int t = threadIdx.x;
  {
    const float4* s4 = (const float4*)Wl;
    float4* d4 = (float4*)wlt;
    for (int i = t; i < DH * DOUT / 4; i += 256) d4[i] = s4[i];
    s4 = (const float4*)W2b;
    d4 = (float4*)wzb;
    for (int i = t; i < DH * DOUT / 4; i += 256) d4[i] = s4[i];
    if (t < 128) ss[t] = scsh[t];
    if (t < DOUT) cvs[t] = cvec[t];
  }
  __syncthreads();
  int rr = t >> 2, q = t & 3;
  int row0 = blockIdx.x * 128 + rr;
  int row1 = row0 + 64;
  bool v0 = row0 < NN, v1 = row1 < NN;
  float y0[10], y1a[10], z0[10], z1[10];
#pragma unroll
  for (int j = 0; j < 10; ++j) {
    float cv = cvs[q * 10 + j];
    y0[j] = cv; y1a[j] = cv; z0[j] = 0.0f; z1[j] = 0.0f;
  }
  const float4* ar0 = (const float4*)(Agg1 + (size_t)row0 * DH);
  const float4* ar1 = (const float4*)(Agg1 + (size_t)row1 * DH);
  const float4 zz = make_float4(0.f, 0.f, 0.f, 0.f);
  for (int k4 = 0; k4 < DH / 4; ++k4) {
    float4 a = v0 ? ar0[k4] : zz;
    float4 b = v1 ? ar1[k4] : zz;
#pragma unroll
    for (int kk = 0; kk < 4; ++kk) {
      int k = k4 * 4 + kk;
      float sck = ss[k], shk = ss[64 + k];
      float xa = fmaxf(fmaf((&a.x)[kk], sck, shk), 0.0f);
      float xb = fmaxf(fmaf((&b.x)[kk], sck, shk), 0.0f);
      const float* wt = wlt + k * DOUT + q * 10;
      const float* wb = wzb + k * DOUT + q * 10;
#pragma unroll
      for (int j = 0; j < 10; ++j) {
        y0[j] = fmaf(xa, wt[j], y0[j]);
        y1a[j] = fmaf(xb, wt[j], y1a[j]);
        z0[j] = fmaf(xa, wb[j], z0[j]);
        z1[j] = fmaf(xb, wb[j], z1[j]);
      }
    }
  }
  if (v0) {
    float2* yo = (float2*)(Y1 + (size_t)row0 * DOUT + q * 10);
#pragma unroll
    for (int p = 0; p < 5; ++p) yo[p] = make_float2(y0[2 * p], y0[2 * p + 1]);
    float di = dinv[row0];
    ushort_t* zp = (ushort_t*)(Z + (size_t)row0 * DOUT + q * 10);
#pragma unroll
    for (int p = 0; p < 5; ++p)
      zp[p] = (ushort_t)f2e4m3(z0[2 * p] * di) | ((ushort_t)f2e4m3(z0[2 * p + 1] * di) << 8);
  }
  if (v1) {
    float2* yo = (float2*)(Y1 + (size_t)row1 * DOUT + q * 10);
#pragma unroll
    for (int p = 0; p < 5; ++p) yo[p] = make_float2(y1a[2 * p], y1a[2 * p + 1]);
    float di = dinv[row1];
    ushort_t* zp = (ushort_t*)(Z + (size_t)row1 * DOUT + q * 10);
#pragma unroll
    for (int p = 0; p < 5; ++p)
      zp[p] = (ushort_t)f2e4m3(z1[2 * p] * di) | ((ushort_t)f2e4m3(z1[2 * p + 1] * di) << 8);
  }
}

// ---- gather2 + log_softmax: 2 nodes/wave, index-prefetch, non-temporal Z loads ----
__global__ void __launch_bounds__(256) k_g2final(const int* __restrict__ csr,
                                                 const int* __restrict__ rowptr,
                                                 const int* __restrict__ cnt,
                                                 const float* __restrict__ dinv,
                                                 const uchar_t* __restrict__ Z,
                                                 const float* __restrict__ Y1,
                                                 float* __restrict__ Out) {
  int lane = threadIdx.x & 63, w = threadIdx.x >> 6;
  int pr = blockIdx.x * 4 + w;  // pair id; grid 12500*4 = 50000 pairs exact
  int d0 = 2 * pr, d1 = d0 + 1;
  int st0 = __builtin_amdgcn_readfirstlane(rowptr[d0]);
  int n0  = __builtin_amdgcn_readfirstlane(cnt[d0]);
  int st1 = __builtin_amdgcn_readfirstlane(rowptr[d1]);
  int n1  = __builtin_amdgcn_readfirstlane(cnt[d1]);
  bool act = lane < DOUT;
  float acc0 = 0.0f, acc1 = 0.0f;
  if (act) {
    acc0 = e4m32f(__builtin_nontemporal_load(&Z[(size_t)d0 * DOUT + lane]));
    acc1 = e4m32f(__builtin_nontemporal_load(&Z[(size_t)d1 * DOUT + lane]));
  }
  const int* cs0 = csr + st0;
  const int* cs1 = csr + st1;
  int nmin = min(n0, n1);
  int k = 0;
  if (nmin >= 4) {
    int a0 = cs0[0], a1 = cs0[1], a2 = cs0[2], a3 = cs0[3];
    int b0 = cs1[0], b1 = cs1[1], b2 = cs1[2], b3 = cs1[3];
    for (; k + 8 <= nmin; k += 4) {
      uchar_t ra0 = 0, ra1 = 0, ra2 = 0, ra3 = 0, rb0 = 0, rb1 = 0, rb2 = 0, rb3 = 0;
      if (act) {
        ra0 = __builtin_nontemporal_load(&Z[(size_t)a0 * DOUT + lane]);
        ra1 = __builtin_nontemporal_load(&Z[(size_t)a1 * DOUT + lane]);
        ra2 = __builtin_nontemporal_load(&Z[(size_t)a2 * DOUT + lane]);
        ra3 = __builtin_nontemporal_load(&Z[(size_t)a3 * DOUT + lane]);
        rb0 = __builtin_nontemporal_load(&Z[(size_t)b0 * DOUT + lane]);
        rb1 = __builtin_nontemporal_load(&Z[(size_t)b1 * DOUT + lane]);
        rb2 = __builtin_nontemporal_load(&Z[(size_t)b2 * DOUT + lane]);
        rb3 = __builtin_nontemporal_load(&Z[(size_t)b3 * DOUT + lane]);
      }
      a0 = cs0[k + 4]; a1 = cs0[k + 5]; a2 = cs0[k + 6]; a3 = cs0[k + 7];
      b0 = cs1[k + 4]; b1 = cs1[k + 5]; b2 = cs1[k + 6]; b3 = cs1[k + 7];
      if (act) {
        acc0 += (e4m32f(ra0) + e4m32f(ra1)) + (e4m32f(ra2) + e4m32f(ra3));
        acc1 += (e4m32f(rb0) + e4m32f(rb1)) + (e4m32f(rb2) + e4m32f(rb3));
      }
    }
    if (act) {
      uchar_t ra0 = __builtin_nontemporal_load(&Z[(size_t)a0 * DOUT + lane]);
      uchar_t ra1 = __builtin_nontemporal_load(&Z[(size_t)a1 * DOUT + lane]);
      uchar_t ra2 = __builtin_nontemporal_load(&Z[(size_t)a2 * DOUT + lane]);
      uchar_t ra3 = __builtin_nontemporal_load(&Z[(size_t)a3 * DOUT + lane]);
      uchar_t rb0 = __builtin_nontemporal_load(&Z[(size_t)b0 * DOUT + lane]);
      uchar_t rb1 = __builtin_nontemporal_load(&Z[(size_t)b1 * DOUT + lane]);
      uchar_t rb2 = __builtin_nontemporal_load(&Z[(size_t)b2 * DOUT + lane]);
      uchar_t rb3 = __builtin_nontemporal_load(&Z[(size_t)b3 * DOUT + lane]);
      acc0 += (e4m32f(ra0) + e4m32f(ra1)) + (e4m32f(ra2) + e4m32f(ra3));
      acc1 += (e4m32f(rb0) + e4m32f(rb1)) + (e4m32f(rb2) + e4m32f(rb3));
    }
    k += 4;
  }
  for (; k < nmin; ++k) {
    int i0 = cs0[k], i1 = cs1[k];
    if (act) {
      acc0 += e4m32f(__builtin_nontemporal_load(&Z[(size_t)i0 * DOUT + lane]));
      acc1 += e4m32f(__builtin_nontemporal_load(&Z[(size_t)i1 * DOUT + lane]));
    }
  }
  int k0 = k;
  for (; k0 + 4 <= n0; k0 += 4) {
    int i0 = cs0[k0], i1 = cs0[k0 + 1], i2 = cs0[k0 + 2], i3 = cs0[k0 + 3];
    if (act) {
      float f0 = e4m32f(__builtin_nontemporal_load(&Z[(size_t)i0 * DOUT + lane]));
      float f1 = e4m32f(__builtin_nontemporal_load(&Z[(size_t)i1 * DOUT + lane]));
      float f2 = e4m32f(__builtin_nontemporal_load(&Z[(size_t)i2 * DOUT + lane]));
      float f3 = e4m32f(__builtin_nontemporal_load(&Z[(size_t)i3 * DOUT + lane]));
      acc0 += (f0 + f1) + (f2 + f3);
    }
  }
  for (; k0 < n0; ++k0) {
    int i = cs0[k0];
    if (act) acc0 += e4m32f(__builtin_nontemporal_load(&Z[(size_t)i * DOUT + lane]));
  }
  int k1 = k;
  for (; k1 + 4 <= n1; k1 += 4) {
    int i0 = cs1[k1], i1 = cs1[k1 + 1], i2 = cs1[k1 + 2], i3 = cs1[k1 + 3];
    if (act) {
      float f0 = e4m32f(__builtin_nontemporal_load(&Z[(size_t)i0 * DOUT + lane]));
      float f1 = e4m32f(__builtin_nontemporal_load(&Z[(size_t)i1 * DOUT + lane]));
      float f2 = e4m32f(__builtin_nontemporal_load(&Z[(size_t)i2 * DOUT + lane]));
      float f3 = e4m32f(__builtin_nontemporal_load(&Z[(size_t)i3 * DOUT + lane]));
      acc1 += (f0 + f1) + (f2 + f3);
    }
  }
  for (; k1 < n1; ++k1) {
    int i = cs1[k1];
    if (act) acc1 += e4m32f(__builtin_nontemporal_load(&Z[(size_t)i * DOUT + lane]));
  }
  // softmax for d0
  {
    float o = act ? (Y1[(size_t)d0 * DOUT + lane] + dinv[d0] * acc0) : -1e30f;
    float m = o;
#pragma unroll
    for (int msk = 1; msk < 64; msk <<= 1) m = fmaxf(m, __shfl_xor(m, msk));
    float ee = act ? __expf(o - m) : 0.0f;
    float ssum = ee;
#pragma unroll
    for (int msk = 1; msk < 64; msk <<= 1) ssum += __shfl_xor(ssum, msk);
    float lse = m + __logf(ssum);
    if (act) Out[(size_t)d0 * DOUT + lane] = o - lse;
  }
  // softmax for d1
  {
    float o = act ? (Y1[(size_t)d1 * DOUT + lane] + dinv[d1] * acc1) : -1e30f;
    float m = o;
#pragma unroll
    for (int msk = 1; msk < 64; msk <<= 1) m = fmaxf(m, __shfl_xor(m, msk));
    float ee = act ? __expf(o - m) : 0.0f;
    float ssum = ee;
#pragma unroll
    for (int msk = 1; msk < 64; msk <<= 1) ssum += __shfl_xor(ssum, msk);
    float lse = m + __logf(ssum);
    if (act) Out[(size_t)d1 * DOUT + lane] = o - lse;
  }
}

extern "C" void kernel_launch(void* const* d_in, const int* in_sizes, int n_in,
                              void* d_out, int out_size, void* d_ws, size_t ws_size,
                              hipStream_t stream) {
  const float* x0  = (const float*)d_in[0];
  const int*   ei  = (const int*)d_in[1];
  const float* W1  = (const float*)d_in[2];
  const float* b1  = (const float*)d_in[3];
  const float* g1  = (const float*)d_in[4];
  const float* be1 = (const float*)d_in[5];
  const float* W2  = (const float*)d_in[6];
  const float* b2  = (const float*)d_in[7];
  const float* Wl  = (const float*)d_in[8];
  const float* bl  = (const float*)d_in[9];
  float* out = (float*)d_out;

  const int* src = ei;
  const int* dst = ei + NE;

  // workspace layout (16B alignment preserved at each buffer)
  char* w8 = (char*)d_ws;
  int*   hist   = (int*)w8;                        // NN
  int*   rowptr = hist + NN;                       // NN (+64 pad)
  float* stats  = (float*)(rowptr + NN + 64);      // 128
  float* scsh   = stats + 128;                     // 128
  float* cvec   = scsh + 128;                      // 64
  float* w2b    = cvec + 64;                       // 2560 (W2 @ Wl_bot)
  float* dinv   = w2b + 2560;                      // NN (+64 pad)
  int*   cntmat = (int*)(dinv + NN + 64);          // 65536
  int*   cscan  = cntmat + N2;                     // 65536
  int*   ctot   = cscan + N2;                      // 64 (+64 pad)
  uint_t* bpair = (uint_t*)(ctot + 128);           // NE u32 (6.4 MB)
  int*   csr    = (int*)(bpair + NE);              // NE (+64 pad)
  ushort_t* Hb  = (ushort_t*)(csr + NE + 64);      // NN*64 bf16 (h1pre)
  float* Agg1   = (float*)(Hb + (size_t)NN * DH);  // NN*64 f32 (agg1)
  float* Y1     = Agg1 + (size_t)NN * DH;          // NN*40 f32
  uchar_t* Z    = (uchar_t*)(Y1 + (size_t)NN * DOUT);  // NN*40 fp8

  const int B = 256;
  int gPr = NN / 8;            // 12500 blocks: 4 waves/block, 2 nodes/wave, exact

  k_cnt<<<PBLK, 512, 0, stream>>>(dst, cntmat, stats);
  k_scanC<<<NB2, 1024, 0, stream>>>(cntmat, cscan, ctot);
  k_scanD<<<NB2, 1024, 0, stream>>>(cscan, ctot);
  k_scat<<<PBLK, 512, 0, stream>>>(src, dst, cscan, bpair);
  k_cfill<<<KB, 512, 0, stream>>>(bpair, cscan, rowptr, hist, dinv, csr);

  k_gemm1<<<GB2, B, 0, stream>>>(x0, W1, dinv, Hb);
  k_gather1<<<2048, B, 0, stream>>>(csr, rowptr, hist, dinv, Hb, b1, Agg1, stats);
  k_bnfinal<<<1, 256, 0, stream>>>(stats, g1, be1, b2, Wl, bl, W2, scsh, cvec, w2b);

  k_bngemm2<<<GB2, B, 0, stream>>>(Agg1, scsh, dinv, Wl, w2b, cvec, Y1, Z);
  k_g2final<<<gPr, B, 0, stream>>>(csr, rowptr, hist, dinv, Z, Y1, out);
}

// Round 16
// 240.893 us; speedup vs baseline: 1.1553x; 1.1553x over previous
//
#include <hip/hip_runtime.h>
#include <hip/hip_fp8.h>
#include <math.h>

#define NN   100000
#define NE   1600000
#define DIN  128
#define DH   64
#define DOUT 40
#define BN_EPS 1e-5f
#define KB   256   // buckets
#define BSZ  391   // nodes per bucket (256*391 = 100096 >= NN)
#define PBLK 256   // partition blocks
#define PE   6250  // NE / PBLK exact
#define N2   (KB * PBLK)  // 65536
#define NB2  64    // N2 / 1024
#define GB2  782   // ceil(NN/128) -- 128 rows per GEMM block

typedef unsigned short ushort_t;
typedef unsigned int uint_t;
typedef unsigned char uchar_t;

__device__ __forceinline__ float bf2f(ushort_t v) {
  union { uint_t u; float f; } w;
  w.u = ((uint_t)v) << 16;
  return w.f;
}
__device__ __forceinline__ ushort_t f2bf(float f) {  // RNE
  union { float f; uint_t u; } w;
  w.f = f;
  uint_t u = w.u;
  u += 0x7fffu + ((u >> 16) & 1u);
  return (ushort_t)(u >> 16);
}
__device__ __forceinline__ uchar_t f2e4m3(float f) {
  __hip_fp8_e4m3 q(f);  // OCP e4m3fn, RNE + satfinite
  return (uchar_t)q.__x;
}
__device__ __forceinline__ float e4m32f(uchar_t b) {
  __hip_fp8_e4m3 q;
  q.__x = (__hip_fp8_storage_t)b;
  return (float)q;
}

// ---------------- pass A: per-block bucket histogram (+stats zero) ----------------
__global__ void __launch_bounds__(512) k_cnt(const int* __restrict__ dst,
                                             int* __restrict__ cntmat,
                                             float* __restrict__ stats) {
  __shared__ int h[KB];
  int t = threadIdx.x, blk = blockIdx.x;
  if (t < KB) h[t] = 0;
  if (blk == 0 && t < 128) stats[t] = 0.0f;
  __syncthreads();
  int base = blk * PE;  // PE = 6250 = 2*3125
  const int2* d2 = (const int2*)(dst + base);
  for (int i = t; i < PE / 2; i += 512) {
    int2 v = d2[i];
    atomicAdd(&h[v.x / BSZ], 1);
    atomicAdd(&h[v.y / BSZ], 1);
  }
  __syncthreads();
  if (t < KB) cntmat[t * PBLK + blk] = h[t];
}

// ---------------- scan C/D: exclusive scan of cntmat (65536, bucket-major) ----------------
__global__ void __launch_bounds__(1024) k_scanC(const int* __restrict__ cntmat,
                                                int* __restrict__ cscan,
                                                int* __restrict__ ctot) {
  __shared__ int sh[1024];
  int t = threadIdx.x, b = blockIdx.x;
  int i = b * 1024 + t;  // exact: 64*1024 = 65536
  int v = cntmat[i];
  sh[t] = v;
  __syncthreads();
  for (int off = 1; off < 1024; off <<= 1) {
    int u = (t >= off) ? sh[t - off] : 0;
    __syncthreads();
    sh[t] += u;
    __syncthreads();
  }
  cscan[i] = sh[t] - v;
  if (t == 1023) ctot[b] = sh[t];
}

__global__ void __launch_bounds__(1024) k_scanD(int* __restrict__ cscan,
                                                const int* __restrict__ ctot) {
  __shared__ int sh[NB2];
  int t = threadIdx.x, b = blockIdx.x;
  if (t < NB2) sh[t] = ctot[t];
  __syncthreads();
  for (int off = 1; off < NB2; off <<= 1) {
    int u = (t >= off && t < NB2) ? sh[t - off] : 0;
    __syncthreads();
    if (t < NB2) sh[t] += u;
    __syncthreads();
  }
  if (b > 0) cscan[b * 1024 + t] += sh[b - 1];
}

// ---------------- pass C: scatter edges to deterministic bucket slots ----------------
// payload = (src << 9) | d_local   (src < 2^17, d_local < 391 < 2^9)
__global__ void __launch_bounds__(512) k_scat(const int* __restrict__ src,
                                              const int* __restrict__ dst,
                                              const int* __restrict__ cscan,
                                              uint_t* __restrict__ bpair) {
  __shared__ int cur[KB];
  int t = threadIdx.x, blk = blockIdx.x;
  if (t < KB) cur[t] = cscan[t * PBLK + blk];
  __syncthreads();
  int base = blk * PE;
  for (int i = t; i < PE; i += 512) {
    int e = base + i;
    int d = dst[e], s = src[e];
    int b = d / BSZ;
    int pos = atomicAdd(&cur[b], 1);
    bpair[pos] = ((uint_t)s << 9) | (uint_t)(d - b * BSZ);
  }
}

// ---- fused: per-bucket count + local scan -> rowptr/hist/dinv + CSR fill ----
__global__ void __launch_bounds__(512) k_cfill(const uint_t* __restrict__ bpair,
                                               const int* __restrict__ cscan,
                                               int* __restrict__ rowptr,
                                               int* __restrict__ hist,
                                               float* __restrict__ dinv,
                                               int* __restrict__ csr) {
  __shared__ int cnt[BSZ];
  __shared__ int loc[BSZ];
  __shared__ int cur[BSZ];
  __shared__ int sh[512];
  int b = blockIdx.x, t = threadIdx.x;
  for (int i = t; i < BSZ; i += 512) { cnt[i] = 0; cur[i] = 0; }
  __syncthreads();
  int start = cscan[b * PBLK];
  int end = (b + 1 < KB) ? cscan[(b + 1) * PBLK] : NE;
  for (int i = start + t; i < end; i += 512) atomicAdd(&cnt[bpair[i] & 511u], 1);
  __syncthreads();
  int v = (t < BSZ) ? cnt[t] : 0;
  sh[t] = v;
  __syncthreads();
  for (int off = 1; off < 512; off <<= 1) {
    int u = (t >= off) ? sh[t - off] : 0;
    __syncthreads();
    sh[t] += u;
    __syncthreads();
  }
  if (t < BSZ) {
    int excl = sh[t] - v;
    loc[t] = excl;
    int node = b * BSZ + t;
    if (node < NN) {
      rowptr[node] = start + excl;
      hist[node] = v;
      dinv[node] = rsqrtf(1.0f + (float)v);
    }
  }
  __syncthreads();
  for (int i = start + t; i < end; i += 512) {
    uint_t u = bpair[i];
    int dloc = (int)(u & 511u);
    int pos = start + loc[dloc] + atomicAdd(&cur[dloc], 1);
    csr[pos] = (int)(u >> 9);
  }
}

// ---------------- h1pre = (x0 @ W1) * dinv, stored bf16 ----------------
// 4 threads per row (16 ch each), 2 rows per thread, W1 staged in LDS.
__global__ void __launch_bounds__(256) k_gemm1(const float* __restrict__ X,
                                               const float* __restrict__ W,
                                               const float* __restrict__ dinv,
                                               ushort_t* __restrict__ Hb) {
  __shared__ float w[DIN * DH];  // 32 KB
  int t = threadIdx.x;
  {
    const float4* ws = (const float4*)W;
    float4* wd = (float4*)w;
#pragma unroll
    for (int i = 0; i < DIN * DH / 4 / 256; ++i) wd[t + i * 256] = ws[t + i * 256];
  }
  __syncthreads();
  int rr = t >> 2, q = t & 3;
  int row0 = blockIdx.x * 128 + rr;
  int row1 = row0 + 64;
  bool v0 = row0 < NN, v1 = row1 < NN;
  float acc0[16], acc1[16];
#pragma unroll
  for (int j = 0; j < 16; ++j) { acc0[j] = 0.0f; acc1[j] = 0.0f; }
  const float4* xr0 = (const float4*)(X + (size_t)row0 * DIN);
  const float4* xr1 = (const float4*)(X + (size_t)row1 * DIN);
  const float4 z4 = make_float4(0.f, 0.f, 0.f, 0.f);
  for (int k4 = 0; k4 < DIN / 4; ++k4) {
    float4 a = v0 ? xr0[k4] : z4;
    float4 b = v1 ? xr1[k4] : z4;
#pragma unroll
    for (int kk = 0; kk < 4; ++kk) {
      const float* wr = w + (k4 * 4 + kk) * DH + q * 16;
      float xa = (&a.x)[kk], xb = (&b.x)[kk];
#pragma unroll
      for (int j = 0; j < 16; ++j) {
        acc0[j] = fmaf(xa, wr[j], acc0[j]);
        acc1[j] = fmaf(xb, wr[j], acc1[j]);
      }
    }
  }
  if (v0) {
    float di = dinv[row0];
    uint_t pk[8];
#pragma unroll
    for (int j = 0; j < 8; ++j)
      pk[j] = (uint_t)f2bf(acc0[2 * j] * di) | ((uint_t)f2bf(acc0[2 * j + 1] * di) << 16);
    uint4* o = (uint4*)(Hb + (size_t)row0 * DH + q * 16);
    o[0] = make_uint4(pk[0], pk[1], pk[2], pk[3]);
    o[1] = make_uint4(pk[4], pk[5], pk[6], pk[7]);
  }
  if (v1) {
    float di = dinv[row1];
    uint_t pk[8];
#pragma unroll
    for (int j = 0; j < 8; ++j)
      pk[j] = (uint_t)f2bf(acc1[2 * j] * di) | ((uint_t)f2bf(acc1[2 * j + 1] * di) << 16);
    uint4* o = (uint4*)(Hb + (size_t)row1 * DH + q * 16);
    o[0] = make_uint4(pk[0], pk[1], pk[2], pk[3]);
    o[1] = make_uint4(pk[4], pk[5], pk[6], pk[7]);
  }
}

// ---- gather1 + BN stats: 2 nodes/wave, index-prefetch software pipeline ----
__global__ void __launch_bounds__(256) k_gather1(const int* __restrict__ csr,
                                                 const int* __restrict__ rowptr,
                                                 const int* __restrict__ cnt,
                                                 const float* __restrict__ dinv,
                                                 const ushort_t* __restrict__ Hb,
                                                 const float* __restrict__ bias,
                                                 float* __restrict__ Agg,
                                                 float* __restrict__ stats) {
  int lane = threadIdx.x & 63, w = threadIdx.x >> 6;
  int c = lane;
  int wid = blockIdx.x * 4 + w;
  int nw = gridDim.x * 4;
  float bc = bias[c];
  float s1 = 0.0f, s2 = 0.0f;
  for (int p = wid; p < NN / 2; p += nw) {
    int d0 = 2 * p, d1 = 2 * p + 1;
    int st0 = __builtin_amdgcn_readfirstlane(rowptr[d0]);
    int n0  = __builtin_amdgcn_readfirstlane(cnt[d0]);
    int st1 = __builtin_amdgcn_readfirstlane(rowptr[d1]);
    int n1  = __builtin_amdgcn_readfirstlane(cnt[d1]);
    const int* cs0 = csr + st0;
    const int* cs1 = csr + st1;
    float acc0 = bf2f(Hb[(size_t)d0 * DH + c]);
    float acc1 = bf2f(Hb[(size_t)d1 * DH + c]);
    int nmin = min(n0, n1);
    int k = 0;
    if (nmin >= 4) {
      // prefetched idx for current batch
      int a0 = cs0[0], a1 = cs0[1], a2 = cs0[2], a3 = cs0[3];
      int b0 = cs1[0], b1 = cs1[1], b2 = cs1[2], b3 = cs1[3];
      for (; k + 8 <= nmin; k += 4) {
        // issue rows for current batch
        ushort_t ra0 = Hb[(size_t)a0 * DH + c];
        ushort_t ra1 = Hb[(size_t)a1 * DH + c];
        ushort_t ra2 = Hb[(size_t)a2 * DH + c];
        ushort_t ra3 = Hb[(size_t)a3 * DH + c];
        ushort_t rb0 = Hb[(size_t)b0 * DH + c];
        ushort_t rb1 = Hb[(size_t)b1 * DH + c];
        ushort_t rb2 = Hb[(size_t)b2 * DH + c];
        ushort_t rb3 = Hb[(size_t)b3 * DH + c];
        // prefetch next batch idx (overlaps with row latency)
        a0 = cs0[k + 4]; a1 = cs0[k + 5]; a2 = cs0[k + 6]; a3 = cs0[k + 7];
        b0 = cs1[k + 4]; b1 = cs1[k + 5]; b2 = cs1[k + 6]; b3 = cs1[k + 7];
        // consume
        acc0 += (bf2f(ra0) + bf2f(ra1)) + (bf2f(ra2) + bf2f(ra3));
        acc1 += (bf2f(rb0) + bf2f(rb1)) + (bf2f(rb2) + bf2f(rb3));
      }
      {  // final full batch with already-loaded idx (k+4 <= nmin guaranteed)
        ushort_t ra0 = Hb[(size_t)a0 * DH + c];
        ushort_t ra1 = Hb[(size_t)a1 * DH + c];
        ushort_t ra2 = Hb[(size_t)a2 * DH + c];
        ushort_t ra3 = Hb[(size_t)a3 * DH + c];
        ushort_t rb0 = Hb[(size_t)b0 * DH + c];
        ushort_t rb1 = Hb[(size_t)b1 * DH + c];
        ushort_t rb2 = Hb[(size_t)b2 * DH + c];
        ushort_t rb3 = Hb[(size_t)b3 * DH + c];
        acc0 += (bf2f(ra0) + bf2f(ra1)) + (bf2f(ra2) + bf2f(ra3));
        acc1 += (bf2f(rb0) + bf2f(rb1)) + (bf2f(rb2) + bf2f(rb3));
        k += 4;
      }
    }
    for (; k < nmin; ++k) {
      acc0 += bf2f(Hb[(size_t)cs0[k] * DH + c]);
      acc1 += bf2f(Hb[(size_t)cs1[k] * DH + c]);
    }
    int k0 = k;
    for (; k0 + 4 <= n0; k0 += 4) {
      int i0 = cs0[k0], i1 = cs0[k0 + 1], i2 = cs0[k0 + 2], i3 = cs0[k0 + 3];
      float f0 = bf2f(Hb[(size_t)i0 * DH + c]);
      float f1 = bf2f(Hb[(size_t)i1 * DH + c]);
      float f2 = bf2f(Hb[(size_t)i2 * DH + c]);
      float f3 = bf2f(Hb[(size_t)i3 * DH + c]);
      acc0 += (f0 + f1) + (f2 + f3);
    }
    for (; k0 < n0; ++k0) acc0 += bf2f(Hb[(size_t)cs0[k0] * DH + c]);
    int k1 = k;
    for (; k1 + 4 <= n1; k1 += 4) {
      int i0 = cs1[k1], i1 = cs1[k1 + 1], i2 = cs1[k1 + 2], i3 = cs1[k1 + 3];
      float f0 = bf2f(Hb[(size_t)i0 * DH + c]);
      float f1 = bf2f(Hb[(size_t)i1 * DH + c]);
      float f2 = bf2f(Hb[(size_t)i2 * DH + c]);
      float f3 = bf2f(Hb[(size_t)i3 * DH + c]);
      acc1 += (f0 + f1) + (f2 + f3);
    }
    for (; k1 < n1; ++k1) acc1 += bf2f(Hb[(size_t)cs1[k1] * DH + c]);
    float v0 = fmaf(acc0, dinv[d0], bc);
    float v1 = fmaf(acc1, dinv[d1], bc);
    Agg[(size_t)d0 * DH + c] = v0;
    Agg[(size_t)d1 * DH + c] = v1;
    s1 += v0 + v1;
    s2 += v0 * v0 + v1 * v1;
  }
  __shared__ float red[512];
  red[threadIdx.x] = s1;
  red[256 + threadIdx.x] = s2;
  __syncthreads();
  if (threadIdx.x < 64) {
    float a = red[c] + red[64 + c] + red[128 + c] + red[192 + c];
    float b = red[256 + c] + red[320 + c] + red[384 + c] + red[448 + c];
    atomicAdd(&stats[c], a);
    atomicAdd(&stats[64 + c], b);
  }
}

// -------- finalize BN: scale/shift; cvec = bl + b2@Wl_bot; W2b = W2 @ Wl_bot --------
__global__ void __launch_bounds__(256) k_bnfinal(const float* __restrict__ stats,
                                                 const float* __restrict__ g,
                                                 const float* __restrict__ be,
                                                 const float* __restrict__ b2,
                                                 const float* __restrict__ Wl,
                                                 const float* __restrict__ bl,
                                                 const float* __restrict__ W2,
                                                 float* __restrict__ scsh,
                                                 float* __restrict__ cvec,
                                                 float* __restrict__ W2b) {
  int t = threadIdx.x;
  if (t < 64) {
    float mean = stats[t] * (1.0f / NN);
    float var = stats[64 + t] * (1.0f / NN) - mean * mean;
    float sc = g[t] * rsqrtf(var + BN_EPS);
    scsh[t] = sc;
    scsh[64 + t] = be[t] - mean * sc;
  }
  if (t < DOUT) {
    float s = bl[t];
    for (int k = 0; k < DH; ++k) s = fmaf(b2[k], Wl[(DH + k) * DOUT + t], s);
    cvec[t] = s;
  }
  // W2b[k][j] = sum_m W2[k][m] * Wl[(64+m)*40 + j]
  {
    int k = t >> 2, jq = (t & 3) * 10;
    float a[10];
#pragma unroll
    for (int j = 0; j < 10; ++j) a[j] = 0.0f;
    for (int m = 0; m < DH; ++m) {
      float wv = W2[k * DH + m];
      const float* wl = Wl + (DH + m) * DOUT + jq;
#pragma unroll
      for (int j = 0; j < 10; ++j) a[j] = fmaf(wv, wl[j], a[j]);
    }
#pragma unroll
    for (int j = 0; j < 10; ++j) W2b[k * DOUT + jq + j] = a[j];
  }
}

// ---- x1 = relu(bn(agg1)); y1 = x1@Wl_top + cvec; z = fp8(dinv * (x1@W2b)) ----
__global__ void __launch_bounds__(256) k_bngemm2(const float* __restrict__ Agg1,
                                                 const float* __restrict__ scsh,
                                                 const float* __restrict__ dinv,
                                                 const float* __restrict__ Wl,
                                                 const float* __restrict__ W2b,
                                                 const float* __restrict__ cvec,
                                                 float* __restrict__ Y1,
                                                 uchar_t* __restrict__ Z) {
  __shared__ float wlt[DH * DOUT];  // 10 KB  (Wl rows 0..63)
  __shared__ float wzb[DH * DOUT];  // 10 KB  (W2 @ Wl_bot)
  __shared__ float ss[128];
  __shared__ float cvs[DOUT];
  int t = threadIdx.x;
  {
    const float4* s4 = (const float4*)Wl;
    float4* d4 = (float4*)wlt;
    for (int i = t; i < DH * DOUT / 4; i += 256) d4[i] = s4[i];
    s4 = (const float4*)W2b;
    d4 = (float4*)wzb;
    for (int i = t; i < DH * DOUT / 4; i += 256) d4[i] = s4[i];
    if (t < 128) ss[t] = scsh[t];
    if (t < DOUT) cvs[t] = cvec[t];
  }
  __syncthreads();
  int rr = t >> 2, q = t & 3;
  int row0 = blockIdx.x * 128 + rr;
  int row1 = row0 + 64;
  bool v0 = row0 < NN, v1 = row1 < NN;
  float y0[10], y1a[10], z0[10], z1[10];
#pragma unroll
  for (int j = 0; j < 10; ++j) {
    float cv = cvs[q * 10 + j];
    y0[j] = cv; y1a[j] = cv; z0[j] = 0.0f; z1[j] = 0.0f;
  }
  const float4* ar0 = (const float4*)(Agg1 + (size_t)row0 * DH);
  const float4* ar1 = (const float4*)(Agg1 + (size_t)row1 * DH);
  const float4 zz = make_float4(0.f, 0.f, 0.f, 0.f);
  for (int k4 = 0; k4 < DH / 4; ++k4) {
    float4 a = v0 ? ar0[k4] : zz;
    float4 b = v1 ? ar1[k4] : zz;
#pragma unroll
    for (int kk = 0; kk < 4; ++kk) {
      int k = k4 * 4 + kk;
      float sck = ss[k], shk = ss[64 + k];
      float xa = fmaxf(fmaf((&a.x)[kk], sck, shk), 0.0f);
      float xb = fmaxf(fmaf((&b.x)[kk], sck, shk), 0.0f);
      const float* wt = wlt + k * DOUT + q * 10;
      const float* wb = wzb + k * DOUT + q * 10;
#pragma unroll
      for (int j = 0; j < 10; ++j) {
        y0[j] = fmaf(xa, wt[j], y0[j]);
        y1a[j] = fmaf(xb, wt[j], y1a[j]);
        z0[j] = fmaf(xa, wb[j], z0[j]);
        z1[j] = fmaf(xb, wb[j], z1[j]);
      }
    }
  }
  if (v0) {
    float2* yo = (float2*)(Y1 + (size_t)row0 * DOUT + q * 10);
#pragma unroll
    for (int p = 0; p < 5; ++p) yo[p] = make_float2(y0[2 * p], y0[2 * p + 1]);
    float di = dinv[row0];
    ushort_t* zp = (ushort_t*)(Z + (size_t)row0 * DOUT + q * 10);
#pragma unroll
    for (int p = 0; p < 5; ++p)
      zp[p] = (ushort_t)f2e4m3(z0[2 * p] * di) | ((ushort_t)f2e4m3(z0[2 * p + 1] * di) << 8);
  }
  if (v1) {
    float2* yo = (float2*)(Y1 + (size_t)row1 * DOUT + q * 10);
#pragma unroll
    for (int p = 0; p < 5; ++p) yo[p] = make_float2(y1a[2 * p], y1a[2 * p + 1]);
    float di = dinv[row1];
    ushort_t* zp = (ushort_t*)(Z + (size_t)row1 * DOUT + q * 10);
#pragma unroll
    for (int p = 0; p < 5; ++p)
      zp[p] = (ushort_t)f2e4m3(z1[2 * p] * di) | ((ushort_t)f2e4m3(z1[2 * p + 1] * di) << 8);
  }
}

// ---- gather2 + log_softmax: 2 nodes/wave, index-prefetch pipeline ----
__global__ void __launch_bounds__(256) k_g2final(const int* __restrict__ csr,
                                                 const int* __restrict__ rowptr,
                                                 const int* __restrict__ cnt,
                                                 const float* __restrict__ dinv,
                                                 const uchar_t* __restrict__ Z,
                                                 const float* __restrict__ Y1,
                                                 float* __restrict__ Out) {
  int lane = threadIdx.x & 63, w = threadIdx.x >> 6;
  int pr = blockIdx.x * 4 + w;  // pair id; grid 12500*4 = 50000 pairs exact
  int d0 = 2 * pr, d1 = d0 + 1;
  int st0 = __builtin_amdgcn_readfirstlane(rowptr[d0]);
  int n0  = __builtin_amdgcn_readfirstlane(cnt[d0]);
  int st1 = __builtin_amdgcn_readfirstlane(rowptr[d1]);
  int n1  = __builtin_amdgcn_readfirstlane(cnt[d1]);
  bool act = lane < DOUT;
  float acc0 = 0.0f, acc1 = 0.0f;
  if (act) {
    acc0 = e4m32f(Z[(size_t)d0 * DOUT + lane]);
    acc1 = e4m32f(Z[(size_t)d1 * DOUT + lane]);
  }
  const int* cs0 = csr + st0;
  const int* cs1 = csr + st1;
  int nmin = min(n0, n1);
  int k = 0;
  if (nmin >= 4) {
    int a0 = cs0[0], a1 = cs0[1], a2 = cs0[2], a3 = cs0[3];
    int b0 = cs1[0], b1 = cs1[1], b2 = cs1[2], b3 = cs1[3];
    for (; k + 8 <= nmin; k += 4) {
      uchar_t ra0 = 0, ra1 = 0, ra2 = 0, ra3 = 0, rb0 = 0, rb1 = 0, rb2 = 0, rb3 = 0;
      if (act) {
        ra0 = Z[(size_t)a0 * DOUT + lane];
        ra1 = Z[(size_t)a1 * DOUT + lane];
        ra2 = Z[(size_t)a2 * DOUT + lane];
        ra3 = Z[(size_t)a3 * DOUT + lane];
        rb0 = Z[(size_t)b0 * DOUT + lane];
        rb1 = Z[(size_t)b1 * DOUT + lane];
        rb2 = Z[(size_t)b2 * DOUT + lane];
        rb3 = Z[(size_t)b3 * DOUT + lane];
      }
      a0 = cs0[k + 4]; a1 = cs0[k + 5]; a2 = cs0[k + 6]; a3 = cs0[k + 7];
      b0 = cs1[k + 4]; b1 = cs1[k + 5]; b2 = cs1[k + 6]; b3 = cs1[k + 7];
      if (act) {
        acc0 += (e4m32f(ra0) + e4m32f(ra1)) + (e4m32f(ra2) + e4m32f(ra3));
        acc1 += (e4m32f(rb0) + e4m32f(rb1)) + (e4m32f(rb2) + e4m32f(rb3));
      }
    }
    if (act) {  // final full batch with preloaded idx
      uchar_t ra0 = Z[(size_t)a0 * DOUT + lane];
      uchar_t ra1 = Z[(size_t)a1 * DOUT + lane];
      uchar_t ra2 = Z[(size_t)a2 * DOUT + lane];
      uchar_t ra3 = Z[(size_t)a3 * DOUT + lane];
      uchar_t rb0 = Z[(size_t)b0 * DOUT + lane];
      uchar_t rb1 = Z[(size_t)b1 * DOUT + lane];
      uchar_t rb2 = Z[(size_t)b2 * DOUT + lane];
      uchar_t rb3 = Z[(size_t)b3 * DOUT + lane];
      acc0 += (e4m32f(ra0) + e4m32f(ra1)) + (e4m32f(ra2) + e4m32f(ra3));
      acc1 += (e4m32f(rb0) + e4m32f(rb1)) + (e4m32f(rb2) + e4m32f(rb3));
    }
    k += 4;
  }
  for (; k < nmin; ++k) {
    int i0 = cs0[k], i1 = cs1[k];
    if (act) {
      acc0 += e4m32f(Z[(size_t)i0 * DOUT + lane]);
      acc1 += e4m32f(Z[(size_t)i1 * DOUT + lane]);
    }
  }
  int k0 = k;
  for (; k0 + 4 <= n0; k0 += 4) {
    int i0 = cs0[k0], i1 = cs0[k0 + 1], i2 = cs0[k0 + 2], i3 = cs0[k0 + 3];
    if (act) {
      float f0 = e4m32f(Z[(size_t)i0 * DOUT + lane]);
      float f1 = e4m32f(Z[(size_t)i1 * DOUT + lane]);
      float f2 = e4m32f(Z[(size_t)i2 * DOUT + lane]);
      float f3 = e4m32f(Z[(size_t)i3 * DOUT + lane]);
      acc0 += (f0 + f1) + (f2 + f3);
    }
  }
  for (; k0 < n0; ++k0) {
    int i = cs0[k0];
    if (act) acc0 += e4m32f(Z[(size_t)i * DOUT + lane]);
  }
  int k1 = k;
  for (; k1 + 4 <= n1; k1 += 4) {
    int i0 = cs1[k1], i1 = cs1[k1 + 1], i2 = cs1[k1 + 2], i3 = cs1[k1 + 3];
    if (act) {
      float f0 = e4m32f(Z[(size_t)i0 * DOUT + lane]);
      float f1 = e4m32f(Z[(size_t)i1 * DOUT + lane]);
      float f2 = e4m32f(Z[(size_t)i2 * DOUT + lane]);
      float f3 = e4m32f(Z[(size_t)i3 * DOUT + lane]);
      acc1 += (f0 + f1) + (f2 + f3);
    }
  }
  for (; k1 < n1; ++k1) {
    int i = cs1[k1];
    if (act) acc1 += e4m32f(Z[(size_t)i * DOUT + lane]);
  }
  // softmax for d0
  {
    float o = act ? (Y1[(size_t)d0 * DOUT + lane] + dinv[d0] * acc0) : -1e30f;
    float m = o;
#pragma unroll
    for (int msk = 1; msk < 64; msk <<= 1) m = fmaxf(m, __shfl_xor(m, msk));
    float ee = act ? __expf(o - m) : 0.0f;
    float ssum = ee;
#pragma unroll
    for (int msk = 1; msk < 64; msk <<= 1) ssum += __shfl_xor(ssum, msk);
    float lse = m + __logf(ssum);
    if (act) Out[(size_t)d0 * DOUT + lane] = o - lse;
  }
  // softmax for d1
  {
    float o = act ? (Y1[(size_t)d1 * DOUT + lane] + dinv[d1] * acc1) : -1e30f;
    float m = o;
#pragma unroll
    for (int msk = 1; msk < 64; msk <<= 1) m = fmaxf(m, __shfl_xor(m, msk));
    float ee = act ? __expf(o - m) : 0.0f;
    float ssum = ee;
#pragma unroll
    for (int msk = 1; msk < 64; msk <<= 1) ssum += __shfl_xor(ssum, msk);
    float lse = m + __logf(ssum);
    if (act) Out[(size_t)d1 * DOUT + lane] = o - lse;
  }
}

extern "C" void kernel_launch(void* const* d_in, const int* in_sizes, int n_in,
                              void* d_out, int out_size, void* d_ws, size_t ws_size,
                              hipStream_t stream) {
  const float* x0  = (const float*)d_in[0];
  const int*   ei  = (const int*)d_in[1];
  const float* W1  = (const float*)d_in[2];
  const float* b1  = (const float*)d_in[3];
  const float* g1  = (const float*)d_in[4];
  const float* be1 = (const float*)d_in[5];
  const float* W2  = (const float*)d_in[6];
  const float* b2  = (const float*)d_in[7];
  const float* Wl  = (const float*)d_in[8];
  const float* bl  = (const float*)d_in[9];
  float* out = (float*)d_out;

  const int* src = ei;
  const int* dst = ei + NE;

  // workspace layout (16B alignment preserved at each buffer)
  char* w8 = (char*)d_ws;
  int*   hist   = (int*)w8;                        // NN
  int*   rowptr = hist + NN;                       // NN (+64 pad)
  float* stats  = (float*)(rowptr + NN + 64);      // 128
  float* scsh   = stats + 128;                     // 128
  float* cvec   = scsh + 128;                      // 64
  float* w2b    = cvec + 64;                       // 2560 (W2 @ Wl_bot)
  float* dinv   = w2b + 2560;                      // NN (+64 pad)
  int*   cntmat = (int*)(dinv + NN + 64);          // 65536
  int*   cscan  = cntmat + N2;                     // 65536
  int*   ctot   = cscan + N2;                      // 64 (+64 pad)
  uint_t* bpair = (uint_t*)(ctot + 128);           // NE u32 (6.4 MB)
  int*   csr    = (int*)(bpair + NE);              // NE (+64 pad)
  ushort_t* Hb  = (ushort_t*)(csr + NE + 64);      // NN*64 bf16 (h1pre)
  float* Agg1   = (float*)(Hb + (size_t)NN * DH);  // NN*64 f32 (agg1)
  float* Y1     = Agg1 + (size_t)NN * DH;          // NN*40 f32
  uchar_t* Z    = (uchar_t*)(Y1 + (size_t)NN * DOUT);  // NN*40 fp8

  const int B = 256;
  int gPr = NN / 8;            // 12500 blocks: 4 waves/block, 2 nodes/wave, exact

  k_cnt<<<PBLK, 512, 0, stream>>>(dst, cntmat, stats);
  k_scanC<<<NB2, 1024, 0, stream>>>(cntmat, cscan, ctot);
  k_scanD<<<NB2, 1024, 0, stream>>>(cscan, ctot);
  k_scat<<<PBLK, 512, 0, stream>>>(src, dst, cscan, bpair);
  k_cfill<<<KB, 512, 0, stream>>>(bpair, cscan, rowptr, hist, dinv, csr);

  k_gemm1<<<GB2, B, 0, stream>>>(x0, W1, dinv, Hb);
  k_gather1<<<2048, B, 0, stream>>>(csr, rowptr, hist, dinv, Hb, b1, Agg1, stats);
  k_bnfinal<<<1, 256, 0, stream>>>(stats, g1, be1, b2, Wl, bl, W2, scsh, cvec, w2b);

  k_bngemm2<<<GB2, B, 0, stream>>>(Agg1, scsh, dinv, Wl, w2b, cvec, Y1, Z);
  k_g2final<<<gPr, B, 0, stream>>>(csr, rowptr, hist, dinv, Z, Y1, out);
}